// Round 2
// baseline (382.887 us; speedup 1.0000x reference)
//
#include <hip/hip_runtime.h>
#include <cstdint>
#include <cstddef>

typedef __attribute__((ext_vector_type(8))) short short8;
typedef __attribute__((ext_vector_type(8))) unsigned short ushort8;
typedef __attribute__((ext_vector_type(4))) float f32x4;

#define DEV static __device__ __forceinline__

DEV unsigned short f2bf(float x) {
  union { float f; unsigned u; } v; v.f = x;
  unsigned r = v.u + 0x7fffu + ((v.u >> 16) & 1u);
  return (unsigned short)(r >> 16);
}
DEV float bf2f(unsigned short u) {
  union { unsigned u; float f; } v; v.u = ((unsigned)u) << 16;
  return v.f;
}
DEV f32x4 mfma16(short8 a, short8 b, f32x4 c) {
  return __builtin_amdgcn_mfma_f32_16x16x32_bf16(a, b, c, 0, 0, 0);
}

constexpr int Bc = 4, Nc = 2048, Dc = 1024, Hc = 16, DKc = 16, DVc = 64, DIc = 1280;
constexpr int Mc = Bc * Nc;  // 8192

// ---------------- elementwise fp32 -> bf16 ----------------
__global__ __launch_bounds__(256) void convert_x(const float* __restrict__ X,
                                                 unsigned short* __restrict__ Xb, int total8) {
  int i = blockIdx.x * 256 + threadIdx.x;
  if (i >= total8) return;
  const float4* p = (const float4*)(X + (size_t)i * 8);
  float4 a = p[0], b = p[1];
  ushort8 o;
  o[0] = f2bf(a.x); o[1] = f2bf(a.y); o[2] = f2bf(a.z); o[3] = f2bf(a.w);
  o[4] = f2bf(b.x); o[5] = f2bf(b.y); o[6] = f2bf(b.z); o[7] = f2bf(b.w);
  *(ushort8*)(Xb + (size_t)i * 8) = o;
}

// ---------------- W[K][N] fp32 -> WT[N][K] bf16 ----------------
__global__ __launch_bounds__(256) void transpose_convert(const float* __restrict__ W,
                                                         unsigned short* __restrict__ WT,
                                                         int K, int N) {
  __shared__ unsigned short t[64][72];
  int k0 = blockIdx.x * 64, n0 = blockIdx.y * 64;
  int tid = threadIdx.x;
#pragma unroll
  for (int it = 0; it < 16; ++it) {
    int f = it * 256 + tid;
    int r = f >> 6, c = f & 63;  // r: k-local, c: n-local (coalesced read)
    t[c][r] = f2bf(W[(size_t)(k0 + r) * N + n0 + c]);
  }
  __syncthreads();
#pragma unroll
  for (int it = 0; it < 16; ++it) {
    int f = it * 256 + tid;
    int r = f >> 6, c = f & 63;  // r: n-local, c: k-local (coalesced write)
    WT[(size_t)(n0 + r) * K + k0 + c] = t[r][c];
  }
}

// ---------------- C[M][N] = A[M][K] * BT[N][K]^T  (bf16 in, bf16/fp32 out) ----------------
template <int OUT_BF16>
__global__ __launch_bounds__(256) void gemm_bt(const unsigned short* __restrict__ A,
                                               const unsigned short* __restrict__ BT,
                                               void* __restrict__ Cout,
                                               int Mq, int Nq, int Kq) {
  __shared__ unsigned short As[128][72];  // +8 pad keeps ds_read_b128 conflict-free
  __shared__ unsigned short Bs[128][72];
  int row0 = blockIdx.x * 128, col0 = blockIdx.y * 128;
  int tid = threadIdx.x, lane = tid & 63, wave = tid >> 6;
  int wm = wave >> 1, wn = wave & 1;  // 2x2 wave grid, each wave 64x64
  int ql = lane >> 4, l16 = lane & 15;
  f32x4 acc[4][4];
#pragma unroll
  for (int i = 0; i < 4; i++)
#pragma unroll
    for (int j = 0; j < 4; j++) acc[i][j] = (f32x4){0.f, 0.f, 0.f, 0.f};

  for (int k0 = 0; k0 < Kq; k0 += 64) {
    __syncthreads();
#pragma unroll
    for (int it = 0; it < 4; ++it) {
      int f = (it * 256 + tid) * 8;
      int r = f >> 6, c = f & 63;
      *(ushort8*)&As[r][c] = *(const ushort8*)&A[(size_t)(row0 + r) * Kq + k0 + c];
      *(ushort8*)&Bs[r][c] = *(const ushort8*)&BT[(size_t)(col0 + r) * Kq + k0 + c];
    }
    __syncthreads();
#pragma unroll
    for (int kk = 0; kk < 64; kk += 32) {
      short8 af[4], bfr[4];
#pragma unroll
      for (int t = 0; t < 4; t++) af[t] = *(const short8*)&As[wm * 64 + t * 16 + l16][kk + ql * 8];
#pragma unroll
      for (int t = 0; t < 4; t++) bfr[t] = *(const short8*)&Bs[wn * 64 + t * 16 + l16][kk + ql * 8];
#pragma unroll
      for (int i = 0; i < 4; i++)
#pragma unroll
        for (int j = 0; j < 4; j++) acc[i][j] = mfma16(af[i], bfr[j], acc[i][j]);
    }
  }
  // epilogue: C/D layout col=lane&15, row=(lane>>4)*4+r (verified m89/m91)
#pragma unroll
  for (int i = 0; i < 4; i++)
#pragma unroll
    for (int j = 0; j < 4; j++)
#pragma unroll
      for (int r = 0; r < 4; r++) {
        int rr = row0 + wm * 64 + i * 16 + ql * 4 + r;
        int cc = col0 + wn * 64 + j * 16 + l16;
        if (OUT_BF16)
          ((unsigned short*)Cout)[(size_t)rr * Nq + cc] = f2bf(acc[i][j][r]);
        else
          ((float*)Cout)[(size_t)rr * Nq + cc] = acc[i][j][r];
      }
}

// ---------------- per-head normalize + gate transform ----------------
// thread id g = (b*16+h)*2048 + n  (head-major: consecutive threads = consecutive n)
__global__ __launch_bounds__(256) void norm_kernel(const unsigned short* __restrict__ QG,
                                                   const unsigned short* __restrict__ KV,
                                                   unsigned short* __restrict__ Qn,
                                                   unsigned short* __restrict__ Kn,
                                                   unsigned short* __restrict__ Vtg,
                                                   unsigned short* __restrict__ G) {
  int g = blockIdx.x * 256 + threadIdx.x;
  int n = g & (Nc - 1), bh = g >> 11;
  int h = bh & 15, b = bh >> 4;
  size_t src = ((size_t)(b * Nc + n)) * DIc + h * 80;

  // queries (16) -> l2norm -> Qn[bh][n][16]
  {
    ushort8 u0 = *(const ushort8*)&QG[src];
    ushort8 u1 = *(const ushort8*)&QG[src + 8];
    float q[16], ss = 0.f;
#pragma unroll
    for (int i = 0; i < 8; i++) { q[i] = bf2f(u0[i]); q[8 + i] = bf2f(u1[i]); }
#pragma unroll
    for (int i = 0; i < 16; i++) ss += q[i] * q[i];
    float sc = 1.f / fmaxf(sqrtf(ss), 1e-12f);
    ushort8 o0, o1;
#pragma unroll
    for (int i = 0; i < 8; i++) { o0[i] = f2bf(q[i] * sc); o1[i] = f2bf(q[8 + i] * sc); }
    size_t dst = ((size_t)bh * Nc + n) * DKc;
    *(ushort8*)&Qn[dst] = o0;
    *(ushort8*)&Qn[dst + 8] = o1;
  }
  // keys (16) -> l2norm -> Kn
  {
    ushort8 u0 = *(const ushort8*)&KV[src];
    ushort8 u1 = *(const ushort8*)&KV[src + 8];
    float q[16], ss = 0.f;
#pragma unroll
    for (int i = 0; i < 8; i++) { q[i] = bf2f(u0[i]); q[8 + i] = bf2f(u1[i]); }
#pragma unroll
    for (int i = 0; i < 16; i++) ss += q[i] * q[i];
    float sc = 1.f / fmaxf(sqrtf(ss), 1e-12f);
    ushort8 o0, o1;
#pragma unroll
    for (int i = 0; i < 8; i++) { o0[i] = f2bf(q[i] * sc); o1[i] = f2bf(q[8 + i] * sc); }
    size_t dst = ((size_t)bh * Nc + n) * DKc;
    *(ushort8*)&Kn[dst] = o0;
    *(ushort8*)&Kn[dst + 8] = o1;
  }
  // values (64) -> l2norm -> transposed Vtg[bh][d][n]  (coalesced across lanes in n)
  {
    ushort8 u[8];
#pragma unroll
    for (int i = 0; i < 8; i++) u[i] = *(const ushort8*)&KV[src + 16 + i * 8];
    float ss = 0.f;
#pragma unroll
    for (int i = 0; i < 8; i++)
#pragma unroll
      for (int j = 0; j < 8; j++) { float x = bf2f(u[i][j]); ss += x * x; }
    float sc = 1.f / fmaxf(sqrtf(ss), 1e-12f);
#pragma unroll
    for (int i = 0; i < 8; i++)
#pragma unroll
      for (int j = 0; j < 8; j++) {
        int d = i * 8 + j;
        Vtg[((size_t)bh * DVc + d) * Nc + n] = f2bf(bf2f(u[i][j]) * sc);
      }
  }
  // gates (64) -> tanh(silu(x)) -> G[bh][n][64]
  {
#pragma unroll
    for (int i = 0; i < 8; i++) {
      ushort8 u = *(const ushort8*)&QG[src + 16 + i * 8];
      ushort8 o;
#pragma unroll
      for (int j = 0; j < 8; j++) {
        float x = bf2f(u[j]);
        float s = x / (1.f + __expf(-x));
        o[j] = f2bf(tanhf(s));
      }
      *(ushort8*)&G[((size_t)bh * Nc + n) * DVc + i * 8] = o;
    }
  }
}

// ---------------- relu^2 attention, fused tanh_norm * gate ----------------
// grid: (B*H, N/128); block 256 = 4 waves
__global__ __launch_bounds__(256) void attn_kernel(const unsigned short* __restrict__ Qn,
                                                   const unsigned short* __restrict__ Kn,
                                                   const unsigned short* __restrict__ Vtg,
                                                   const unsigned short* __restrict__ G,
                                                   unsigned short* __restrict__ outpre) {
  __shared__ unsigned short Qs[128][40];   // 16 dims + 16 zero-pad (K=32) + 8 pad
  __shared__ unsigned short Ks[128][40];
  __shared__ unsigned short Vt[64][136];   // V^T tile: [d][key]
  union PsU {
    unsigned short ps[128][136];           // P tile (bf16, A-layout source)
    float of[128][65];                     // O tile for epilogue (aliased after final sync)
  };
  __shared__ PsU U;

  int bh = blockIdx.x;
  int b = bh >> 4, h = bh & 15;
  int q0 = blockIdx.y * 128;
  int tid = threadIdx.x, lane = tid & 63, wave = tid >> 6;
  int ql = lane >> 4, l16 = lane & 15;
  int qw = wave >> 1, kw = wave & 1;  // S-phase: q-half, key-half; PV-phase: q-half, d-half

  // stage Q tile once (zero-padded to 32 dims)
  {
    int row = tid >> 1, half = tid & 1;
    *(ushort8*)&Qs[row][half * 8] =
        *(const ushort8*)&Qn[((size_t)bh * Nc + q0 + row) * DKc + half * 8];
    ushort8 z = {0, 0, 0, 0, 0, 0, 0, 0};
    *(ushort8*)&Qs[row][16 + half * 8] = z;
  }

  f32x4 oacc[4][2];
#pragma unroll
  for (int i = 0; i < 4; i++) { oacc[i][0] = (f32x4){0.f,0.f,0.f,0.f}; oacc[i][1] = (f32x4){0.f,0.f,0.f,0.f}; }

  for (int kt = 0; kt < Nc / 128; ++kt) {
    int k0 = kt * 128;
    __syncthreads();  // prior PV reads of Ps/Vt done before restaging
    {
      int row = tid >> 1, half = tid & 1;
      *(ushort8*)&Ks[row][half * 8] =
          *(const ushort8*)&Kn[((size_t)bh * Nc + k0 + row) * DKc + half * 8];
      ushort8 z = {0, 0, 0, 0, 0, 0, 0, 0};
      *(ushort8*)&Ks[row][16 + half * 8] = z;
    }
#pragma unroll
    for (int p = 0; p < 4; ++p) {  // V^T rows straight from pre-transposed Vtg
      int f = (p * 256 + tid) * 8;
      int d = f >> 7, kc = f & 127;
      *(ushort8*)&Vt[d][kc] = *(const ushort8*)&Vtg[((size_t)bh * DVc + d) * Nc + k0 + kc];
    }
    __syncthreads();

    // S = Q K^T  (one K=32 MFMA step, dims 16..31 are zeros)
    f32x4 sacc[4][4];
#pragma unroll
    for (int i = 0; i < 4; i++)
#pragma unroll
      for (int j = 0; j < 4; j++) sacc[i][j] = (f32x4){0.f, 0.f, 0.f, 0.f};
    {
      short8 aq[4], bk[4];
#pragma unroll
      for (int t = 0; t < 4; t++) aq[t] = *(const short8*)&Qs[qw * 64 + t * 16 + l16][ql * 8];
#pragma unroll
      for (int t = 0; t < 4; t++) bk[t] = *(const short8*)&Ks[kw * 64 + t * 16 + l16][ql * 8];
#pragma unroll
      for (int i = 0; i < 4; i++)
#pragma unroll
        for (int j = 0; j < 4; j++) sacc[i][j] = mfma16(aq[i], bk[j], sacc[i][j]);
    }
    // P = relu(S)^2 -> LDS (C-layout -> memory, re-read in A-layout)
#pragma unroll
    for (int i = 0; i < 4; i++)
#pragma unroll
      for (int j = 0; j < 4; j++)
#pragma unroll
        for (int r = 0; r < 4; r++) {
          float v = fmaxf(sacc[i][j][r], 0.f);
          v = v * v;
          int rr = qw * 64 + i * 16 + ql * 4 + r;
          int cc = kw * 64 + j * 16 + l16;
          U.ps[rr][cc] = f2bf(v);
        }
    __syncthreads();

    // O += P V   (PV-phase: wave covers q in [qw*64,+64), d in [kw*32,+32))
#pragma unroll
    for (int ks = 0; ks < 4; ++ks) {
      short8 ap[4], bv[2];
#pragma unroll
      for (int t = 0; t < 4; t++)
        ap[t] = *(const short8*)&U.ps[qw * 64 + t * 16 + l16][ks * 32 + ql * 8];
#pragma unroll
      for (int t = 0; t < 2; t++)
        bv[t] = *(const short8*)&Vt[kw * 32 + t * 16 + l16][ks * 32 + ql * 8];
#pragma unroll
      for (int i = 0; i < 4; i++)
#pragma unroll
        for (int j = 0; j < 2; j++) oacc[i][j] = mfma16(ap[i], bv[j], oacc[i][j]);
    }
  }
  __syncthreads();
  // spill O to LDS fp32 for cross-wave row norms
#pragma unroll
  for (int i = 0; i < 4; i++)
#pragma unroll
    for (int j = 0; j < 2; j++)
#pragma unroll
      for (int r = 0; r < 4; r++) {
        int rr = qw * 64 + i * 16 + ql * 4 + r;
        int cc = kw * 32 + j * 16 + l16;
        U.of[rr][cc] = oacc[i][j][r];
      }
  __syncthreads();
  if (tid < 128) {
    int row = tid;
    float ss = 0.f;
#pragma unroll
    for (int d = 0; d < DVc; ++d) { float x = U.of[row][d]; ss += x * x; }
    float nrm = sqrtf(ss);
    float sc = tanhf(nrm) / fmaxf(nrm, 1e-12f);
    size_t gbase = ((size_t)bh * Nc + q0 + row) * DVc;
    size_t obase = ((size_t)(b * Nc + q0 + row)) * (Hc * DVc) + h * DVc;
#pragma unroll
    for (int i = 0; i < 8; i++) {
      ushort8 gu = *(const ushort8*)&G[gbase + i * 8];
      ushort8 o;
#pragma unroll
      for (int j = 0; j < 8; j++) o[j] = f2bf(U.of[row][i * 8 + j] * sc * bf2f(gu[j]));
      *(ushort8*)&outpre[obase + i * 8] = o;
    }
  }
}

extern "C" void kernel_launch(void* const* d_in, const int* in_sizes, int n_in,
                              void* d_out, int out_size, void* d_ws, size_t ws_size,
                              hipStream_t stream) {
  const float* X = (const float*)d_in[0];     // (4,2048,1024)
  const float* Wqg = (const float*)d_in[1];   // (1024,1280)
  const float* Wkv = (const float*)d_in[2];   // (1024,1280)
  const float* Wout = (const float*)d_in[3];  // (1024,1024)
  float* out = (float*)d_out;
  (void)in_sizes; (void)n_in; (void)out_size; (void)ws_size;

  char* ws = (char*)d_ws;
  size_t off = 0;
  auto alloc = [&](size_t bytes) {
    void* p = ws + off;
    off += (bytes + 255) & ~(size_t)255;
    return p;
  };
  // NOTE (R1 fix): Qn/Kn/Vtg/G are per-(b,h) tensors — B*H*N*{DK,DV}, NOT Mc*{DK,DV}.
  // The R0 sizes were 16x too small; norm_kernel overflowed across buffers.
  unsigned short* Xbf   = (unsigned short*)alloc((size_t)Mc * Dc * 2);            // 16 MB
  unsigned short* WqgT  = (unsigned short*)alloc((size_t)DIc * Dc * 2);           // 2.5 MB
  unsigned short* WkvT  = (unsigned short*)alloc((size_t)DIc * Dc * 2);
  unsigned short* WoutT = (unsigned short*)alloc((size_t)Dc * Dc * 2);            // 2 MB
  unsigned short* QG    = (unsigned short*)alloc((size_t)Mc * DIc * 2);           // 20 MB
  unsigned short* KV    = (unsigned short*)alloc((size_t)Mc * DIc * 2);           // 20 MB
  unsigned short* Qn    = (unsigned short*)alloc((size_t)Bc * Hc * Nc * DKc * 2); // 4 MB
  unsigned short* Kn    = (unsigned short*)alloc((size_t)Bc * Hc * Nc * DKc * 2); // 4 MB
  unsigned short* Vtg   = (unsigned short*)alloc((size_t)Bc * Hc * Nc * DVc * 2); // 16 MB
  unsigned short* G     = (unsigned short*)alloc((size_t)Bc * Hc * Nc * DVc * 2); // 16 MB
  // outpre aliases Xbf: Xbf is dead after the two projection GEMMs (stream-ordered
  // before attn_kernel writes outpre). Same size: Mc*Hc*DVc == Mc*Dc.
  unsigned short* outpre = Xbf;

  convert_x<<<(Mc * Dc / 8) / 256, 256, 0, stream>>>(X, Xbf, Mc * Dc / 8);
  transpose_convert<<<dim3(Dc / 64, DIc / 64), 256, 0, stream>>>(Wqg, WqgT, Dc, DIc);
  transpose_convert<<<dim3(Dc / 64, DIc / 64), 256, 0, stream>>>(Wkv, WkvT, Dc, DIc);
  transpose_convert<<<dim3(Dc / 64, Dc / 64), 256, 0, stream>>>(Wout, WoutT, Dc, Dc);
  gemm_bt<1><<<dim3(Mc / 128, DIc / 128), 256, 0, stream>>>(Xbf, WqgT, QG, Mc, DIc, Dc);
  gemm_bt<1><<<dim3(Mc / 128, DIc / 128), 256, 0, stream>>>(Xbf, WkvT, KV, Mc, DIc, Dc);
  norm_kernel<<<(Mc * Hc) / 256, 256, 0, stream>>>(QG, KV, Qn, Kn, Vtg, G);
  attn_kernel<<<dim3(Bc * Hc, Nc / 128), 256, 0, stream>>>(Qn, Kn, Vtg, G, outpre);
  gemm_bt<0><<<dim3(Mc / 128, Dc / 128), 256, 0, stream>>>(outpre, WoutT, out, Mc, Dc, Dc);
}

// Round 3
// 358.065 us; speedup vs baseline: 1.0693x; 1.0693x over previous
//
#include <hip/hip_runtime.h>
#include <cstdint>
#include <cstddef>

typedef __attribute__((ext_vector_type(8))) short short8;
typedef __attribute__((ext_vector_type(8))) unsigned short ushort8;
typedef __attribute__((ext_vector_type(4))) float f32x4;

#define DEV static __device__ __forceinline__

DEV unsigned short f2bf(float x) {
  union { float f; unsigned u; } v; v.f = x;
  unsigned r = v.u + 0x7fffu + ((v.u >> 16) & 1u);
  return (unsigned short)(r >> 16);
}
DEV float bf2f(unsigned short u) {
  union { unsigned u; float f; } v; v.u = ((unsigned)u) << 16;
  return v.f;
}
// pack two fp32 -> bf16x2 dword, round-half-up (1-ulp-tie bias, fine at P scale)
DEV unsigned pack2bf(float lo, float hi) {
  union { float f; unsigned u; } a, b; a.f = lo; b.f = hi;
  return ((b.u + 0x8000u) & 0xFFFF0000u) | ((a.u + 0x8000u) >> 16);
}
DEV f32x4 mfma16(short8 a, short8 b, f32x4 c) {
  return __builtin_amdgcn_mfma_f32_16x16x32_bf16(a, b, c, 0, 0, 0);
}

constexpr int Bc = 4, Nc = 2048, Dc = 1024, Hc = 16, DKc = 16, DVc = 64, DIc = 1280;
constexpr int Mc = Bc * Nc;  // 8192

// ---------------- elementwise fp32 -> bf16 ----------------
__global__ __launch_bounds__(256) void convert_x(const float* __restrict__ X,
                                                 unsigned short* __restrict__ Xb, int total8) {
  int i = blockIdx.x * 256 + threadIdx.x;
  if (i >= total8) return;
  const float4* p = (const float4*)(X + (size_t)i * 8);
  float4 a = p[0], b = p[1];
  ushort8 o;
  o[0] = f2bf(a.x); o[1] = f2bf(a.y); o[2] = f2bf(a.z); o[3] = f2bf(a.w);
  o[4] = f2bf(b.x); o[5] = f2bf(b.y); o[6] = f2bf(b.z); o[7] = f2bf(b.w);
  *(ushort8*)(Xb + (size_t)i * 8) = o;
}

// ---------------- W[K][N] fp32 -> WT[N][K] bf16 ----------------
__global__ __launch_bounds__(256) void transpose_convert(const float* __restrict__ W,
                                                         unsigned short* __restrict__ WT,
                                                         int K, int N) {
  __shared__ unsigned short t[64][72];
  int k0 = blockIdx.x * 64, n0 = blockIdx.y * 64;
  int tid = threadIdx.x;
#pragma unroll
  for (int it = 0; it < 16; ++it) {
    int f = it * 256 + tid;
    int r = f >> 6, c = f & 63;
    t[c][r] = f2bf(W[(size_t)(k0 + r) * N + n0 + c]);
  }
  __syncthreads();
#pragma unroll
  for (int it = 0; it < 16; ++it) {
    int f = it * 256 + tid;
    int r = f >> 6, c = f & 63;
    WT[(size_t)(n0 + r) * K + k0 + c] = t[r][c];
  }
}

// ---------------- C[M][N] = A[M][K] * BT[N][K]^T  (bf16 in, bf16/fp32 out) ----------------
template <int OUT_BF16>
__global__ __launch_bounds__(256) void gemm_bt(const unsigned short* __restrict__ A,
                                               const unsigned short* __restrict__ BT,
                                               void* __restrict__ Cout,
                                               int Mq, int Nq, int Kq) {
  __shared__ unsigned short As[128][72];
  __shared__ unsigned short Bs[128][72];
  int row0 = blockIdx.x * 128, col0 = blockIdx.y * 128;
  int tid = threadIdx.x, lane = tid & 63, wave = tid >> 6;
  int wm = wave >> 1, wn = wave & 1;
  int ql = lane >> 4, l16 = lane & 15;
  f32x4 acc[4][4];
#pragma unroll
  for (int i = 0; i < 4; i++)
#pragma unroll
    for (int j = 0; j < 4; j++) acc[i][j] = (f32x4){0.f, 0.f, 0.f, 0.f};

  for (int k0 = 0; k0 < Kq; k0 += 64) {
    __syncthreads();
#pragma unroll
    for (int it = 0; it < 4; ++it) {
      int f = (it * 256 + tid) * 8;
      int r = f >> 6, c = f & 63;
      *(ushort8*)&As[r][c] = *(const ushort8*)&A[(size_t)(row0 + r) * Kq + k0 + c];
      *(ushort8*)&Bs[r][c] = *(const ushort8*)&BT[(size_t)(col0 + r) * Kq + k0 + c];
    }
    __syncthreads();
#pragma unroll
    for (int kk = 0; kk < 64; kk += 32) {
      short8 af[4], bfr[4];
#pragma unroll
      for (int t = 0; t < 4; t++) af[t] = *(const short8*)&As[wm * 64 + t * 16 + l16][kk + ql * 8];
#pragma unroll
      for (int t = 0; t < 4; t++) bfr[t] = *(const short8*)&Bs[wn * 64 + t * 16 + l16][kk + ql * 8];
#pragma unroll
      for (int i = 0; i < 4; i++)
#pragma unroll
        for (int j = 0; j < 4; j++) acc[i][j] = mfma16(af[i], bfr[j], acc[i][j]);
    }
  }
#pragma unroll
  for (int i = 0; i < 4; i++)
#pragma unroll
    for (int j = 0; j < 4; j++)
#pragma unroll
      for (int r = 0; r < 4; r++) {
        int rr = row0 + wm * 64 + i * 16 + ql * 4 + r;
        int cc = col0 + wn * 64 + j * 16 + l16;
        if (OUT_BF16)
          ((unsigned short*)Cout)[(size_t)rr * Nq + cc] = f2bf(acc[i][j][r]);
        else
          ((float*)Cout)[(size_t)rr * Nq + cc] = acc[i][j][r];
      }
}

// ---------------- per-head normalize + gate transform ----------------
__global__ __launch_bounds__(256) void norm_kernel(const unsigned short* __restrict__ QG,
                                                   const unsigned short* __restrict__ KV,
                                                   unsigned short* __restrict__ Qn,
                                                   unsigned short* __restrict__ Kn,
                                                   unsigned short* __restrict__ Vtg,
                                                   unsigned short* __restrict__ G) {
  int g = blockIdx.x * 256 + threadIdx.x;
  int n = g & (Nc - 1), bh = g >> 11;
  int h = bh & 15, b = bh >> 4;
  size_t src = ((size_t)(b * Nc + n)) * DIc + h * 80;

  {
    ushort8 u0 = *(const ushort8*)&QG[src];
    ushort8 u1 = *(const ushort8*)&QG[src + 8];
    float q[16], ss = 0.f;
#pragma unroll
    for (int i = 0; i < 8; i++) { q[i] = bf2f(u0[i]); q[8 + i] = bf2f(u1[i]); }
#pragma unroll
    for (int i = 0; i < 16; i++) ss += q[i] * q[i];
    float sc = 1.f / fmaxf(sqrtf(ss), 1e-12f);
    ushort8 o0, o1;
#pragma unroll
    for (int i = 0; i < 8; i++) { o0[i] = f2bf(q[i] * sc); o1[i] = f2bf(q[8 + i] * sc); }
    size_t dst = ((size_t)bh * Nc + n) * DKc;
    *(ushort8*)&Qn[dst] = o0;
    *(ushort8*)&Qn[dst + 8] = o1;
  }
  {
    ushort8 u0 = *(const ushort8*)&KV[src];
    ushort8 u1 = *(const ushort8*)&KV[src + 8];
    float q[16], ss = 0.f;
#pragma unroll
    for (int i = 0; i < 8; i++) { q[i] = bf2f(u0[i]); q[8 + i] = bf2f(u1[i]); }
#pragma unroll
    for (int i = 0; i < 16; i++) ss += q[i] * q[i];
    float sc = 1.f / fmaxf(sqrtf(ss), 1e-12f);
    ushort8 o0, o1;
#pragma unroll
    for (int i = 0; i < 8; i++) { o0[i] = f2bf(q[i] * sc); o1[i] = f2bf(q[8 + i] * sc); }
    size_t dst = ((size_t)bh * Nc + n) * DKc;
    *(ushort8*)&Kn[dst] = o0;
    *(ushort8*)&Kn[dst + 8] = o1;
  }
  {
    ushort8 u[8];
#pragma unroll
    for (int i = 0; i < 8; i++) u[i] = *(const ushort8*)&KV[src + 16 + i * 8];
    float ss = 0.f;
#pragma unroll
    for (int i = 0; i < 8; i++)
#pragma unroll
      for (int j = 0; j < 8; j++) { float x = bf2f(u[i][j]); ss += x * x; }
    float sc = 1.f / fmaxf(sqrtf(ss), 1e-12f);
#pragma unroll
    for (int i = 0; i < 8; i++)
#pragma unroll
      for (int j = 0; j < 8; j++) {
        int d = i * 8 + j;
        Vtg[((size_t)bh * DVc + d) * Nc + n] = f2bf(bf2f(u[i][j]) * sc);
      }
  }
  {
#pragma unroll
    for (int i = 0; i < 8; i++) {
      ushort8 u = *(const ushort8*)&QG[src + 16 + i * 8];
      ushort8 o;
#pragma unroll
      for (int j = 0; j < 8; j++) {
        float x = bf2f(u[j]);
        float s = x / (1.f + __expf(-x));
        o[j] = f2bf(tanhf(s));
      }
      *(ushort8*)&G[((size_t)bh * Nc + n) * DVc + i * 8] = o;
    }
  }
}

// ---------------- relu^2 attention, fused tanh_norm * gate ----------------
// grid: (N/128, B*H); block 256 = 4 waves. 52.2 KB LDS -> 3 blocks/CU.
// S computed operand-swapped (A=K, B=Q) so C-regs hold 4 contiguous keys of one
// Ps row -> packed b64 P writes (R2 had 64 scalar b16 writes/thread/tile, 29%
// of cycles in bank-conflict stalls). Q frags live in registers; K frags come
// straight from global (L2-resident, 328 KB/bh working set). 2 barriers/tile.
__global__ __launch_bounds__(256, 3) void attn_kernel(const unsigned short* __restrict__ Qn,
                                                      const unsigned short* __restrict__ Kn,
                                                      const unsigned short* __restrict__ Vtg,
                                                      const unsigned short* __restrict__ G,
                                                      unsigned short* __restrict__ outpre) {
  __shared__ unsigned short Vt[64][136];   // V^T tile: [d][key], 17408 B
  union PsU {
    unsigned short ps[128][136];           // P tile [q][key], 34816 B; stride 136:
                                           // b64 writes & b128 reads both bank-minimal
    float of[128][65];                     // O tile for epilogue (aliased, 33280 B)
  };
  __shared__ PsU U;

  int bh = blockIdx.y;
  int b = bh >> 4, h = bh & 15;
  int q0 = blockIdx.x * 128;
  int tid = threadIdx.x, lane = tid & 63, wave = tid >> 6;
  int ql = lane >> 4, l16 = lane & 15;
  int qw = wave >> 1, kw = wave & 1;  // PV-phase: q-half, d-half

  const short8 zz = {0, 0, 0, 0, 0, 0, 0, 0};

  // Q fragments (B-operand), resident all kernel: n=l16 -> q, k=ql*8+j -> dim.
  // dims 16..31 are the K=32 zero-pad (ql>=2 lanes hold zeros).
  short8 qf[8];
#pragma unroll
  for (int qt = 0; qt < 8; ++qt)
    qf[qt] = (ql < 2)
                 ? *(const short8*)&Qn[((size_t)bh * Nc + q0 + qt * 16 + l16) * DKc + ql * 8]
                 : zz;

  f32x4 oacc[4][2];
#pragma unroll
  for (int i = 0; i < 4; i++) { oacc[i][0] = (f32x4){0.f,0.f,0.f,0.f}; oacc[i][1] = (f32x4){0.f,0.f,0.f,0.f}; }

  for (int kt = 0; kt < Nc / 128; ++kt) {
    int k0 = kt * 128;
    __syncthreads();  // prior PV reads of Ps/Vt done before restaging
#pragma unroll
    for (int p = 0; p < 4; ++p) {  // stage V^T tile
      int f = (p * 256 + tid) * 8;
      int d = f >> 7, kc = f & 127;
      *(ushort8*)&Vt[d][kc] = *(const ushort8*)&Vtg[((size_t)bh * DVc + d) * Nc + k0 + kc];
    }
    // S phase: wave owns keys [wave*32, wave*32+32); computes all 128 q for them.
#pragma unroll
    for (int kh = 0; kh < 2; ++kh) {
      short8 kf = (ql < 2)
                      ? *(const short8*)&Kn[((size_t)bh * Nc + k0 + wave * 32 + kh * 16 + l16) * DKc + ql * 8]
                      : zz;
      int colbase = wave * 32 + kh * 16 + ql * 4;
#pragma unroll
      for (int qt = 0; qt < 8; ++qt) {
        f32x4 s = mfma16(kf, qf[qt], (f32x4){0.f, 0.f, 0.f, 0.f});
        // C layout: col(l16)=q within qt-tile, row(ql*4+r)=key -> s[r] = 4 contiguous keys
        float a0 = fmaxf(s[0], 0.f); a0 *= a0;
        float a1 = fmaxf(s[1], 0.f); a1 *= a1;
        float a2 = fmaxf(s[2], 0.f); a2 *= a2;
        float a3 = fmaxf(s[3], 0.f); a3 *= a3;
        uint2 w2;
        w2.x = pack2bf(a0, a1);
        w2.y = pack2bf(a2, a3);
        *(uint2*)&U.ps[qt * 16 + l16][colbase] = w2;  // 8B aligned: 136*2 % 8 == 0, colbase*2 % 8 == 0
      }
    }
    __syncthreads();
    // O += P V   (wave: q in [qw*64,+64), d in [kw*32,+32)) — verified R2 structure
#pragma unroll
    for (int ks = 0; ks < 4; ++ks) {
      short8 ap[4], bv[2];
#pragma unroll
      for (int t = 0; t < 4; t++)
        ap[t] = *(const short8*)&U.ps[qw * 64 + t * 16 + l16][ks * 32 + ql * 8];
#pragma unroll
      for (int t = 0; t < 2; t++)
        bv[t] = *(const short8*)&Vt[kw * 32 + t * 16 + l16][ks * 32 + ql * 8];
#pragma unroll
      for (int i = 0; i < 4; i++)
#pragma unroll
        for (int j = 0; j < 2; j++) oacc[i][j] = mfma16(ap[i], bv[j], oacc[i][j]);
    }
  }
  __syncthreads();
#pragma unroll
  for (int i = 0; i < 4; i++)
#pragma unroll
    for (int j = 0; j < 2; j++)
#pragma unroll
      for (int r = 0; r < 4; r++) {
        int rr = qw * 64 + i * 16 + ql * 4 + r;
        int cc = kw * 32 + j * 16 + l16;
        U.of[rr][cc] = oacc[i][j][r];
      }
  __syncthreads();
  if (tid < 128) {
    int row = tid;
    float ss = 0.f;
#pragma unroll
    for (int d = 0; d < DVc; ++d) { float x = U.of[row][d]; ss += x * x; }
    float nrm = sqrtf(ss);
    float sc = tanhf(nrm) / fmaxf(nrm, 1e-12f);
    size_t gbase = ((size_t)bh * Nc + q0 + row) * DVc;
    size_t obase = ((size_t)(b * Nc + q0 + row)) * (Hc * DVc) + h * DVc;
#pragma unroll
    for (int i = 0; i < 8; i++) {
      ushort8 gu = *(const ushort8*)&G[gbase + i * 8];
      ushort8 o;
#pragma unroll
      for (int j = 0; j < 8; j++) o[j] = f2bf(U.of[row][i * 8 + j] * sc * bf2f(gu[j]));
      *(ushort8*)&outpre[obase + i * 8] = o;
    }
  }
}

extern "C" void kernel_launch(void* const* d_in, const int* in_sizes, int n_in,
                              void* d_out, int out_size, void* d_ws, size_t ws_size,
                              hipStream_t stream) {
  const float* X = (const float*)d_in[0];     // (4,2048,1024)
  const float* Wqg = (const float*)d_in[1];   // (1024,1280)
  const float* Wkv = (const float*)d_in[2];   // (1024,1280)
  const float* Wout = (const float*)d_in[3];  // (1024,1024)
  float* out = (float*)d_out;
  (void)in_sizes; (void)n_in; (void)out_size; (void)ws_size;

  char* ws = (char*)d_ws;
  size_t off = 0;
  auto alloc = [&](size_t bytes) {
    void* p = ws + off;
    off += (bytes + 255) & ~(size_t)255;
    return p;
  };
  unsigned short* Xbf   = (unsigned short*)alloc((size_t)Mc * Dc * 2);            // 16 MB
  unsigned short* WqgT  = (unsigned short*)alloc((size_t)DIc * Dc * 2);           // 2.5 MB
  unsigned short* WkvT  = (unsigned short*)alloc((size_t)DIc * Dc * 2);
  unsigned short* WoutT = (unsigned short*)alloc((size_t)Dc * Dc * 2);            // 2 MB
  unsigned short* QG    = (unsigned short*)alloc((size_t)Mc * DIc * 2);           // 20 MB
  unsigned short* KV    = (unsigned short*)alloc((size_t)Mc * DIc * 2);           // 20 MB
  unsigned short* Qn    = (unsigned short*)alloc((size_t)Bc * Hc * Nc * DKc * 2); // 4 MB
  unsigned short* Kn    = (unsigned short*)alloc((size_t)Bc * Hc * Nc * DKc * 2); // 4 MB
  unsigned short* Vtg   = (unsigned short*)alloc((size_t)Bc * Hc * Nc * DVc * 2); // 16 MB
  unsigned short* G     = (unsigned short*)alloc((size_t)Bc * Hc * Nc * DVc * 2); // 16 MB
  // outpre aliases Xbf (dead after projection GEMMs; same size Mc*Dc)
  unsigned short* outpre = Xbf;

  convert_x<<<(Mc * Dc / 8) / 256, 256, 0, stream>>>(X, Xbf, Mc * Dc / 8);
  transpose_convert<<<dim3(Dc / 64, DIc / 64), 256, 0, stream>>>(Wqg, WqgT, Dc, DIc);
  transpose_convert<<<dim3(Dc / 64, DIc / 64), 256, 0, stream>>>(Wkv, WkvT, Dc, DIc);
  transpose_convert<<<dim3(Dc / 64, Dc / 64), 256, 0, stream>>>(Wout, WoutT, Dc, Dc);
  gemm_bt<1><<<dim3(Mc / 128, DIc / 128), 256, 0, stream>>>(Xbf, WqgT, QG, Mc, DIc, Dc);
  gemm_bt<1><<<dim3(Mc / 128, DIc / 128), 256, 0, stream>>>(Xbf, WkvT, KV, Mc, DIc, Dc);
  norm_kernel<<<(Mc * Hc) / 256, 256, 0, stream>>>(QG, KV, Qn, Kn, Vtg, G);
  attn_kernel<<<dim3(Nc / 128, Bc * Hc), 256, 0, stream>>>(Qn, Kn, Vtg, G, outpre);
  gemm_bt<0><<<dim3(Mc / 128, Dc / 128), 256, 0, stream>>>(outpre, WoutT, out, Mc, Dc, Dc);
}

// Round 4
// 324.707 us; speedup vs baseline: 1.1792x; 1.1027x over previous
//
#include <hip/hip_runtime.h>
#include <cstdint>
#include <cstddef>

typedef __attribute__((ext_vector_type(8))) short short8;
typedef __attribute__((ext_vector_type(8))) unsigned short ushort8;
typedef __attribute__((ext_vector_type(4))) float f32x4;

#define DEV static __device__ __forceinline__

DEV unsigned short f2bf(float x) {
  union { float f; unsigned u; } v; v.f = x;
  unsigned r = v.u + 0x7fffu + ((v.u >> 16) & 1u);
  return (unsigned short)(r >> 16);
}
DEV float bf2f(unsigned short u) {
  union { unsigned u; float f; } v; v.u = ((unsigned)u) << 16;
  return v.f;
}
DEV unsigned pack2bf(float lo, float hi) {
  union { float f; unsigned u; } a, b; a.f = lo; b.f = hi;
  return ((b.u + 0x8000u) & 0xFFFF0000u) | ((a.u + 0x8000u) >> 16);
}
DEV f32x4 mfma16(short8 a, short8 b, f32x4 c) {
  return __builtin_amdgcn_mfma_f32_16x16x32_bf16(a, b, c, 0, 0, 0);
}

// async global->LDS, 16B per lane; LDS dst is wave-uniform base + lane*16
typedef __attribute__((address_space(1))) unsigned int g_u32;
typedef __attribute__((address_space(3))) unsigned int l_u32;
DEV void glds16(const unsigned short* g, unsigned short* l) {
  __builtin_amdgcn_global_load_lds((g_u32*)g, (l_u32*)l, 16, 0, 0);
}

constexpr int Bc = 4, Nc = 2048, Dc = 1024, Hc = 16, DKc = 16, DVc = 64, DIc = 1280;
constexpr int Mc = Bc * Nc;  // 8192

// ---------------- elementwise fp32 -> bf16 ----------------
__global__ __launch_bounds__(256) void convert_x(const float* __restrict__ X,
                                                 unsigned short* __restrict__ Xb, int total8) {
  int i = blockIdx.x * 256 + threadIdx.x;
  if (i >= total8) return;
  const float4* p = (const float4*)(X + (size_t)i * 8);
  float4 a = p[0], b = p[1];
  ushort8 o;
  o[0] = f2bf(a.x); o[1] = f2bf(a.y); o[2] = f2bf(a.z); o[3] = f2bf(a.w);
  o[4] = f2bf(b.x); o[5] = f2bf(b.y); o[6] = f2bf(b.z); o[7] = f2bf(b.w);
  *(ushort8*)(Xb + (size_t)i * 8) = o;
}

// ---------------- W[K][N] fp32 -> WT[N][K] bf16 ----------------
__global__ __launch_bounds__(256) void transpose_convert(const float* __restrict__ W,
                                                         unsigned short* __restrict__ WT,
                                                         int K, int N) {
  __shared__ unsigned short t[64][72];
  int k0 = blockIdx.x * 64, n0 = blockIdx.y * 64;
  int tid = threadIdx.x;
#pragma unroll
  for (int it = 0; it < 16; ++it) {
    int f = it * 256 + tid;
    int r = f >> 6, c = f & 63;
    t[c][r] = f2bf(W[(size_t)(k0 + r) * N + n0 + c]);
  }
  __syncthreads();
#pragma unroll
  for (int it = 0; it < 16; ++it) {
    int f = it * 256 + tid;
    int r = f >> 6, c = f & 63;
    WT[(size_t)(n0 + r) * K + k0 + c] = t[r][c];
  }
}

// ---------------- C[M][N] = A[M][K] * BT[N][K]^T, m97-style global_load_lds ----------------
// LDS is UNPADDED (global_load_lds constraint) with XOR swizzle: row r, 8-elem
// colblock cb lives at 16B-slot r*8 + (cb ^ (r&7)). Staging lane (r8=lane>>3)
// fetches global colblock (lane&7)^r8 so HW's base+lane*16 lands it at the
// swizzled slot. Fragment ds_read_b128 banks: 4*(cb^(row&7)) — 16 rows cover
// all 32 banks exactly 2x (structural b128 minimum).
template <int OUT_BF16>
__global__ __launch_bounds__(256) void gemm_glds(const unsigned short* __restrict__ A,
                                                 const unsigned short* __restrict__ BT,
                                                 void* __restrict__ Cout,
                                                 int Mq, int Nq, int Kq) {
  __shared__ unsigned short As[128 * 64];
  __shared__ unsigned short Bs[128 * 64];
  int row0 = blockIdx.x * 128, col0 = blockIdx.y * 128;
  int tid = threadIdx.x, lane = tid & 63, wave = tid >> 6;
  int wm = wave >> 1, wn = wave & 1;
  int ql = lane >> 4, l16 = lane & 15;
  int r8 = lane >> 3, cbl = (lane & 7) ^ r8;  // staging: lane's row-in-chunk, swizzled colblock

  const unsigned short* gA = A + (size_t)(row0 + wave * 32 + r8) * Kq + cbl * 8;
  const unsigned short* gB = BT + (size_t)(col0 + wave * 32 + r8) * Kq + cbl * 8;

  f32x4 acc[4][4];
#pragma unroll
  for (int i = 0; i < 4; i++)
#pragma unroll
    for (int j = 0; j < 4; j++) acc[i][j] = (f32x4){0.f, 0.f, 0.f, 0.f};

  for (int k0 = 0; k0 < Kq; k0 += 64) {
    __syncthreads();
#pragma unroll
    for (int i = 0; i < 4; ++i) {  // wave stages rows [wave*32, +32): 4 chunks of 8 rows
      glds16(gA + (size_t)(i * 8) * Kq + k0, &As[(wave * 32 + i * 8) * 64]);
      glds16(gB + (size_t)(i * 8) * Kq + k0, &Bs[(wave * 32 + i * 8) * 64]);
    }
    __syncthreads();  // compiler emits vmcnt(0) drain before s_barrier
#pragma unroll
    for (int kk = 0; kk < 64; kk += 32) {
      short8 af[4], bfr[4];
#pragma unroll
      for (int t = 0; t < 4; t++) {
        int row = wm * 64 + t * 16 + l16;
        int cb = (kk >> 3) + ql;
        af[t] = *(const short8*)&As[row * 64 + ((cb ^ (row & 7)) << 3)];
      }
#pragma unroll
      for (int t = 0; t < 4; t++) {
        int row = wn * 64 + t * 16 + l16;
        int cb = (kk >> 3) + ql;
        bfr[t] = *(const short8*)&Bs[row * 64 + ((cb ^ (row & 7)) << 3)];
      }
#pragma unroll
      for (int i = 0; i < 4; i++)
#pragma unroll
        for (int j = 0; j < 4; j++) acc[i][j] = mfma16(af[i], bfr[j], acc[i][j]);
    }
  }
#pragma unroll
  for (int i = 0; i < 4; i++)
#pragma unroll
    for (int j = 0; j < 4; j++)
#pragma unroll
      for (int r = 0; r < 4; r++) {
        int rr = row0 + wm * 64 + i * 16 + ql * 4 + r;
        int cc = col0 + wn * 64 + j * 16 + l16;
        if (OUT_BF16)
          ((unsigned short*)Cout)[(size_t)rr * Nq + cc] = f2bf(acc[i][j][r]);
        else
          ((float*)Cout)[(size_t)rr * Nq + cc] = acc[i][j][r];
      }
}

// ---------------- per-head normalize + gate transform ----------------
__global__ __launch_bounds__(256) void norm_kernel(const unsigned short* __restrict__ QG,
                                                   const unsigned short* __restrict__ KV,
                                                   unsigned short* __restrict__ Qn,
                                                   unsigned short* __restrict__ Kn,
                                                   unsigned short* __restrict__ Vtg,
                                                   unsigned short* __restrict__ G) {
  int g = blockIdx.x * 256 + threadIdx.x;
  int n = g & (Nc - 1), bh = g >> 11;
  int h = bh & 15, b = bh >> 4;
  size_t src = ((size_t)(b * Nc + n)) * DIc + h * 80;

  {
    ushort8 u0 = *(const ushort8*)&QG[src];
    ushort8 u1 = *(const ushort8*)&QG[src + 8];
    float q[16], ss = 0.f;
#pragma unroll
    for (int i = 0; i < 8; i++) { q[i] = bf2f(u0[i]); q[8 + i] = bf2f(u1[i]); }
#pragma unroll
    for (int i = 0; i < 16; i++) ss += q[i] * q[i];
    float sc = 1.f / fmaxf(sqrtf(ss), 1e-12f);
    ushort8 o0, o1;
#pragma unroll
    for (int i = 0; i < 8; i++) { o0[i] = f2bf(q[i] * sc); o1[i] = f2bf(q[8 + i] * sc); }
    size_t dst = ((size_t)bh * Nc + n) * DKc;
    *(ushort8*)&Qn[dst] = o0;
    *(ushort8*)&Qn[dst + 8] = o1;
  }
  {
    ushort8 u0 = *(const ushort8*)&KV[src];
    ushort8 u1 = *(const ushort8*)&KV[src + 8];
    float q[16], ss = 0.f;
#pragma unroll
    for (int i = 0; i < 8; i++) { q[i] = bf2f(u0[i]); q[8 + i] = bf2f(u1[i]); }
#pragma unroll
    for (int i = 0; i < 16; i++) ss += q[i] * q[i];
    float sc = 1.f / fmaxf(sqrtf(ss), 1e-12f);
    ushort8 o0, o1;
#pragma unroll
    for (int i = 0; i < 8; i++) { o0[i] = f2bf(q[i] * sc); o1[i] = f2bf(q[8 + i] * sc); }
    size_t dst = ((size_t)bh * Nc + n) * DKc;
    *(ushort8*)&Kn[dst] = o0;
    *(ushort8*)&Kn[dst + 8] = o1;
  }
  {
    ushort8 u[8];
#pragma unroll
    for (int i = 0; i < 8; i++) u[i] = *(const ushort8*)&KV[src + 16 + i * 8];
    float ss = 0.f;
#pragma unroll
    for (int i = 0; i < 8; i++)
#pragma unroll
      for (int j = 0; j < 8; j++) { float x = bf2f(u[i][j]); ss += x * x; }
    float sc = 1.f / fmaxf(sqrtf(ss), 1e-12f);
#pragma unroll
    for (int i = 0; i < 8; i++)
#pragma unroll
      for (int j = 0; j < 8; j++) {
        int d = i * 8 + j;
        Vtg[((size_t)bh * DVc + d) * Nc + n] = f2bf(bf2f(u[i][j]) * sc);
      }
  }
  {
#pragma unroll
    for (int i = 0; i < 8; i++) {
      ushort8 u = *(const ushort8*)&QG[src + 16 + i * 8];
      ushort8 o;
#pragma unroll
      for (int j = 0; j < 8; j++) {
        float x = bf2f(u[j]);
        float s = x / (1.f + __expf(-x));
        o[j] = f2bf(tanhf(s));
      }
      *(ushort8*)&G[((size_t)bh * Nc + n) * DVc + i * 8] = o;
    }
  }
}

// ---------------- relu^2 attention, fused tanh_norm * gate ----------------
// 1024 linear blocks; XCD-aware map: xcd=gid&7 owns bh in [xcd*8, xcd*8+8)
// so each per-XCD L2 fetches only 8 heads' K/V (R3: all 64 -> 92MB refetch).
// K frags + V regs for tile kt+1 prefetched during tile kt compute.
__global__ __launch_bounds__(256, 3) void attn_kernel(const unsigned short* __restrict__ Qn,
                                                      const unsigned short* __restrict__ Kn,
                                                      const unsigned short* __restrict__ Vtg,
                                                      const unsigned short* __restrict__ G,
                                                      unsigned short* __restrict__ outpre) {
  __shared__ unsigned short Vt[64][136];
  union PsU {
    unsigned short ps[128][136];
    float of[128][65];
  };
  __shared__ PsU U;

  int gid = blockIdx.x;
  int xcd = gid & 7, slot = gid >> 3;
  int bh = xcd * 8 + (slot & 7);
  int q0 = (slot >> 3) * 128;
  int b = bh >> 4, h = bh & 15;
  int tid = threadIdx.x, lane = tid & 63, wave = tid >> 6;
  int ql = lane >> 4, l16 = lane & 15;
  int qw = wave >> 1, kw = wave & 1;

  const short8 zz = {0, 0, 0, 0, 0, 0, 0, 0};

  // Q fragments (B-operand), resident all kernel
  short8 qf[8];
#pragma unroll
  for (int qt = 0; qt < 8; ++qt)
    qf[qt] = (ql < 2)
                 ? *(const short8*)&Qn[((size_t)bh * Nc + q0 + qt * 16 + l16) * DKc + ql * 8]
                 : zz;

  // V staging coords (tid-fixed)
  int vd[4], vkc[4];
#pragma unroll
  for (int p = 0; p < 4; ++p) {
    int f = (p * 256 + tid) * 8;
    vd[p] = f >> 7; vkc[p] = f & 127;
  }

  // prefetch tile 0
  short8 kf_cur[2], kf_nxt[2];
  ushort8 vb[4], vb_n[4];
#pragma unroll
  for (int kh = 0; kh < 2; ++kh)
    kf_cur[kh] = (ql < 2)
                     ? *(const short8*)&Kn[((size_t)bh * Nc + 0 + wave * 32 + kh * 16 + l16) * DKc + ql * 8]
                     : zz;
#pragma unroll
  for (int p = 0; p < 4; ++p)
    vb[p] = *(const ushort8*)&Vtg[((size_t)bh * DVc + vd[p]) * Nc + 0 + vkc[p]];

  f32x4 oacc[4][2];
#pragma unroll
  for (int i = 0; i < 4; i++) { oacc[i][0] = (f32x4){0.f,0.f,0.f,0.f}; oacc[i][1] = (f32x4){0.f,0.f,0.f,0.f}; }

  for (int kt = 0; kt < Nc / 128; ++kt) {
    int k0 = kt * 128;
    __syncthreads();  // prior PV reads of Ps/Vt done
    // stage prefetched V regs -> LDS
#pragma unroll
    for (int p = 0; p < 4; ++p) *(ushort8*)&Vt[vd[p]][vkc[p]] = vb[p];
    // issue next tile's global loads (overlap S+PV compute)
    if (kt < Nc / 128 - 1) {
      int kn0 = k0 + 128;
#pragma unroll
      for (int kh = 0; kh < 2; ++kh)
        kf_nxt[kh] = (ql < 2)
                         ? *(const short8*)&Kn[((size_t)bh * Nc + kn0 + wave * 32 + kh * 16 + l16) * DKc + ql * 8]
                         : zz;
#pragma unroll
      for (int p = 0; p < 4; ++p)
        vb_n[p] = *(const ushort8*)&Vtg[((size_t)bh * DVc + vd[p]) * Nc + kn0 + vkc[p]];
    } else {
#pragma unroll
      for (int kh = 0; kh < 2; ++kh) kf_nxt[kh] = zz;
#pragma unroll
      for (int p = 0; p < 4; ++p) vb_n[p] = (ushort8){0,0,0,0,0,0,0,0};
    }
    // S phase: wave owns keys [wave*32, +32); A=K, B=Q -> C holds 4 contiguous keys/reg
#pragma unroll
    for (int kh = 0; kh < 2; ++kh) {
      int colbase = wave * 32 + kh * 16 + ql * 4;
#pragma unroll
      for (int qt = 0; qt < 8; ++qt) {
        f32x4 s = mfma16(kf_cur[kh], qf[qt], (f32x4){0.f, 0.f, 0.f, 0.f});
        float a0 = fmaxf(s[0], 0.f); a0 *= a0;
        float a1 = fmaxf(s[1], 0.f); a1 *= a1;
        float a2 = fmaxf(s[2], 0.f); a2 *= a2;
        float a3 = fmaxf(s[3], 0.f); a3 *= a3;
        uint2 w2;
        w2.x = pack2bf(a0, a1);
        w2.y = pack2bf(a2, a3);
        *(uint2*)&U.ps[qt * 16 + l16][colbase] = w2;
      }
    }
    __syncthreads();
    // O += P V
#pragma unroll
    for (int ks = 0; ks < 4; ++ks) {
      short8 ap[4], bv[2];
#pragma unroll
      for (int t = 0; t < 4; t++)
        ap[t] = *(const short8*)&U.ps[qw * 64 + t * 16 + l16][ks * 32 + ql * 8];
#pragma unroll
      for (int t = 0; t < 2; t++)
        bv[t] = *(const short8*)&Vt[kw * 32 + t * 16 + l16][ks * 32 + ql * 8];
#pragma unroll
      for (int i = 0; i < 4; i++)
#pragma unroll
        for (int j = 0; j < 2; j++) oacc[i][j] = mfma16(ap[i], bv[j], oacc[i][j]);
    }
#pragma unroll
    for (int kh = 0; kh < 2; ++kh) kf_cur[kh] = kf_nxt[kh];
#pragma unroll
    for (int p = 0; p < 4; ++p) vb[p] = vb_n[p];
  }
  __syncthreads();
#pragma unroll
  for (int i = 0; i < 4; i++)
#pragma unroll
    for (int j = 0; j < 2; j++)
#pragma unroll
      for (int r = 0; r < 4; r++) {
        int rr = qw * 64 + i * 16 + ql * 4 + r;
        int cc = kw * 32 + j * 16 + l16;
        U.of[rr][cc] = oacc[i][j][r];
      }
  __syncthreads();
  if (tid < 128) {
    int row = tid;
    float ss = 0.f;
#pragma unroll
    for (int d = 0; d < DVc; ++d) { float x = U.of[row][d]; ss += x * x; }
    float nrm = sqrtf(ss);
    float sc = tanhf(nrm) / fmaxf(nrm, 1e-12f);
    size_t gbase = ((size_t)bh * Nc + q0 + row) * DVc;
    size_t obase = ((size_t)(b * Nc + q0 + row)) * (Hc * DVc) + h * DVc;
#pragma unroll
    for (int i = 0; i < 8; i++) {
      ushort8 gu = *(const ushort8*)&G[gbase + i * 8];
      ushort8 o;
#pragma unroll
      for (int j = 0; j < 8; j++) o[j] = f2bf(U.of[row][i * 8 + j] * sc * bf2f(gu[j]));
      *(ushort8*)&outpre[obase + i * 8] = o;
    }
  }
}

extern "C" void kernel_launch(void* const* d_in, const int* in_sizes, int n_in,
                              void* d_out, int out_size, void* d_ws, size_t ws_size,
                              hipStream_t stream) {
  const float* X = (const float*)d_in[0];     // (4,2048,1024)
  const float* Wqg = (const float*)d_in[1];   // (1024,1280)
  const float* Wkv = (const float*)d_in[2];   // (1024,1280)
  const float* Wout = (const float*)d_in[3];  // (1024,1024)
  float* out = (float*)d_out;
  (void)in_sizes; (void)n_in; (void)out_size; (void)ws_size;

  char* ws = (char*)d_ws;
  size_t off = 0;
  auto alloc = [&](size_t bytes) {
    void* p = ws + off;
    off += (bytes + 255) & ~(size_t)255;
    return p;
  };
  unsigned short* Xbf   = (unsigned short*)alloc((size_t)Mc * Dc * 2);            // 16 MB
  unsigned short* WqgT  = (unsigned short*)alloc((size_t)DIc * Dc * 2);           // 2.5 MB
  unsigned short* WkvT  = (unsigned short*)alloc((size_t)DIc * Dc * 2);
  unsigned short* WoutT = (unsigned short*)alloc((size_t)Dc * Dc * 2);            // 2 MB
  unsigned short* QG    = (unsigned short*)alloc((size_t)Mc * DIc * 2);           // 20 MB
  unsigned short* KV    = (unsigned short*)alloc((size_t)Mc * DIc * 2);           // 20 MB
  unsigned short* Qn    = (unsigned short*)alloc((size_t)Bc * Hc * Nc * DKc * 2); // 4 MB
  unsigned short* Kn    = (unsigned short*)alloc((size_t)Bc * Hc * Nc * DKc * 2); // 4 MB
  unsigned short* Vtg   = (unsigned short*)alloc((size_t)Bc * Hc * Nc * DVc * 2); // 16 MB
  unsigned short* G     = (unsigned short*)alloc((size_t)Bc * Hc * Nc * DVc * 2); // 16 MB
  unsigned short* outpre = Xbf;  // Xbf dead after projection GEMMs; same size

  convert_x<<<(Mc * Dc / 8) / 256, 256, 0, stream>>>(X, Xbf, Mc * Dc / 8);
  transpose_convert<<<dim3(Dc / 64, DIc / 64), 256, 0, stream>>>(Wqg, WqgT, Dc, DIc);
  transpose_convert<<<dim3(Dc / 64, DIc / 64), 256, 0, stream>>>(Wkv, WkvT, Dc, DIc);
  transpose_convert<<<dim3(Dc / 64, Dc / 64), 256, 0, stream>>>(Wout, WoutT, Dc, Dc);
  gemm_glds<1><<<dim3(Mc / 128, DIc / 128), 256, 0, stream>>>(Xbf, WqgT, QG, Mc, DIc, Dc);
  gemm_glds<1><<<dim3(Mc / 128, DIc / 128), 256, 0, stream>>>(Xbf, WkvT, KV, Mc, DIc, Dc);
  norm_kernel<<<(Mc * Hc) / 256, 256, 0, stream>>>(QG, KV, Qn, Kn, Vtg, G);
  attn_kernel<<<1024, 256, 0, stream>>>(Qn, Kn, Vtg, G, outpre);
  gemm_glds<0><<<dim3(Mc / 128, Dc / 128), 256, 0, stream>>>(outpre, WoutT, out, Mc, Dc, Dc);
}